// Round 6
// baseline (20859.264 us; speedup 1.0000x reference)
//
#include <hip/hip_runtime.h>
#include <math.h>

#define KP 8192
#define TSTEPS 4096
#define BLOCK 1024
#define PT 8                 // particles per thread
#define NWAVES 16
#define NBUCK 8192           // bucket table (avg occupancy 1)
#define NBF 8192.0f
#define INV_NB (1.0f / 8192.0f)

// ---------------- DPP wave-scan helpers (pure VALU, no LDS pipe) ----------------
template <int CTRL, int RM>
__device__ __forceinline__ float dpp_add_f(float x) {
  int s = __builtin_amdgcn_update_dpp(0, __float_as_int(x), CTRL, RM, 0xF, false);
  return x + __int_as_float(s);
}
template <int CTRL, int RM>
__device__ __forceinline__ int dpp_max_i(int x) {
  int s = __builtin_amdgcn_update_dpp(0, x, CTRL, RM, 0xF, false);
  return x > s ? x : s;
}
__device__ __forceinline__ float wscan64_add(float x) {
  x = dpp_add_f<0x111, 0xF>(x); x = dpp_add_f<0x112, 0xF>(x);
  x = dpp_add_f<0x114, 0xF>(x); x = dpp_add_f<0x118, 0xF>(x);
  x = dpp_add_f<0x142, 0xA>(x); x = dpp_add_f<0x143, 0xC>(x);
  return x;
}
__device__ __forceinline__ int wscan64_max(int x) {
  x = dpp_max_i<0x111, 0xF>(x); x = dpp_max_i<0x112, 0xF>(x);
  x = dpp_max_i<0x114, 0xF>(x); x = dpp_max_i<0x118, 0xF>(x);
  x = dpp_max_i<0x142, 0xA>(x); x = dpp_max_i<0x143, 0xC>(x);
  return x;
}
__device__ __forceinline__ float rscan16_add(float x) {
  x = dpp_add_f<0x111, 0xF>(x); x = dpp_add_f<0x112, 0xF>(x);
  x = dpp_add_f<0x114, 0xF>(x); x = dpp_add_f<0x118, 0xF>(x);
  return x;
}
__device__ __forceinline__ int rscan16_max(int x) {
  x = dpp_max_i<0x111, 0xF>(x); x = dpp_max_i<0x112, 0xF>(x);
  x = dpp_max_i<0x114, 0xF>(x); x = dpp_max_i<0x118, 0xF>(x);
  return x;
}
__device__ __forceinline__ float readlane_f(float v, int l) {
  return __int_as_float(__builtin_amdgcn_readlane(__float_as_int(v), l));
}

// ---------------------------------------------------------------------------
// Transpose z [KP][TSTEPS] -> zT [TSTEPS][KP].
// ---------------------------------------------------------------------------
__global__ void transpose_k(const float* __restrict__ in, float* __restrict__ out) {
  __shared__ float tile[32][33];
  const int c0 = blockIdx.x * 32;
  const int r0 = blockIdx.y * 32;
  const int tx = threadIdx.x;
  const int ty = threadIdx.y;
#pragma unroll
  for (int i = 0; i < 32; i += 8)
    tile[ty + i][tx] = in[(size_t)(r0 + ty + i) * TSTEPS + c0 + tx];
  __syncthreads();
#pragma unroll
  for (int i = 0; i < 32; i += 8)
    out[(size_t)(c0 + ty + i) * KP + r0 + tx] = tile[tx][ty + i];
}

// ---------------------------------------------------------------------------
// Persistent single-workgroup SMC scan. Normalized in-LDS CDF, bucket table
// with scatter + hierarchical max-scan, interp-start + binary in-bucket search.
// ---------------------------------------------------------------------------
template <bool ZTRANS>
__global__ __launch_bounds__(BLOCK) void smc_scan(const float* __restrict__ x,
                                                  const float* __restrict__ w0,
                                                  const float* __restrict__ zsrc,
                                                  const float* __restrict__ u,
                                                  float* __restrict__ out) {
  extern __shared__ float sm[];
  float* wbufA = sm;                     // KP
  float* wbufB = sm + KP;                // KP
  float* cdf_s = sm + 2 * KP;            // KP: normalized cdf, LINEAR layout
  float* cend  = cdf_s + KP;             // BLOCK: per-thread cdf end values
  float* red   = cend + BLOCK;           // NWAVES: float wave totals
  int*   redi  = (int*)(red + NWAVES);   // NWAVES: int wave maxes
  int*   bcI   = redi + NWAVES;          // 4: broadcast (fhiLast)
  int*   L_s   = bcI + 4;                // NBUCK+1: bucket -> lower_bound idx

  const int tid = threadIdx.x;
  const int lane = tid & 63;
  const int wid = tid >> 6;
  const int kbase = tid * PT;

  float* wcur = wbufA;
  float* wnxt = wbufB;

  for (int i = tid; i < NBUCK; i += BLOCK) L_s[i] = 0;
  if (tid == 0) L_s[NBUCK] = KP - 1;  // sentinel, never cleared

  float wv[PT];
  {
    float4 a = *(const float4*)(w0 + kbase);
    float4 b = *(const float4*)(w0 + kbase + 4);
    wv[0] = a.x; wv[1] = a.y; wv[2] = a.z; wv[3] = a.w;
    wv[4] = b.x; wv[5] = b.y; wv[6] = b.z; wv[7] = b.w;
    *(float4*)(wcur + kbase) = a;
    *(float4*)(wcur + kbase + 4) = b;
  }
  __syncthreads();

  // One-step-ahead prefetch registers.
  float zn[PT], un[PT];
  float xt_next = x[0];
  if (ZTRANS) {
    float4 a = *(const float4*)(zsrc + kbase);
    float4 b = *(const float4*)(zsrc + kbase + 4);
    zn[0] = a.x; zn[1] = a.y; zn[2] = a.z; zn[3] = a.w;
    zn[4] = b.x; zn[5] = b.y; zn[6] = b.z; zn[7] = b.w;
  } else {
#pragma unroll
    for (int j = 0; j < PT; ++j) zn[j] = zsrc[(size_t)(kbase + j) * TSTEPS];
  }
  {
    float4 a = *(const float4*)(u + kbase);
    float4 b = *(const float4*)(u + kbase + 4);
    un[0] = a.x; un[1] = a.y; un[2] = a.z; un[3] = a.w;
    un[4] = b.x; un[5] = b.y; un[6] = b.z; un[7] = b.w;
  }

  float acc = 0.f;

  for (int t = 0; t < TSTEPS; ++t) {
    float zv[PT], uv[PT];
#pragma unroll
    for (int j = 0; j < PT; ++j) { zv[j] = zn[j]; uv[j] = un[j]; }
    const float xt = xt_next;

    if (t + 1 < TSTEPS) {
      xt_next = x[t + 1];
      if (ZTRANS) {
        float4 a = *(const float4*)(zsrc + (size_t)(t + 1) * KP + kbase);
        float4 b = *(const float4*)(zsrc + (size_t)(t + 1) * KP + kbase + 4);
        zn[0] = a.x; zn[1] = a.y; zn[2] = a.z; zn[3] = a.w;
        zn[4] = b.x; zn[5] = b.y; zn[6] = b.z; zn[7] = b.w;
      } else {
#pragma unroll
        for (int j = 0; j < PT; ++j)
          zn[j] = zsrc[(size_t)(kbase + j) * TSTEPS + t + 1];
      }
      float4 a = *(const float4*)(u + (size_t)(t + 1) * KP + kbase);
      float4 b = *(const float4*)(u + (size_t)(t + 1) * KP + kbase + 4);
      un[0] = a.x; un[1] = a.y; un[2] = a.z; un[3] = a.w;
      un[4] = b.x; un[5] = b.y; un[6] = b.z; un[7] = b.w;
    }

    // ---- A: shifted weights, exp (fp32 range suffices: w is a permutation
    // of w0), thread-local inclusive scan, DPP wave scan.
    float s[PT];
    float run = 0.f;
#pragma unroll
    for (int j = 0; j < PT; ++j) {
      float d = zv[j] - wv[j];
      float lw = fmaf(xt, zv[j], -0.5f * d * d);
      run += __expf(lw);
      s[j] = run;
    }
    const float wincl = wscan64_add(run);
    const float wexcl = wincl - run;
    if (lane == 63) red[wid] = wincl;
    __syncthreads();  // B1 (also: prev-step D/E LDS reads all done)

    // ---- B: cross-wave float scan (replicated per row, DPP).
    float v16 = rscan16_add(red[lane & 15]);
    const float total = readlane_f(v16, 15);
    const float wpre = wid ? readlane_f(v16, wid - 1) : 0.f;
    const float base = wpre + wexcl;
    const float invT = 1.0f / total;  // uniform across block

    // ---- C1: NORMALIZED cdf (search target becomes u itself), b128 writes
    // (linear layout, conflict-free), cend for exact telescoping, clear L.
    float cvn[PT];
#pragma unroll
    for (int j = 0; j < PT; ++j) cvn[j] = (base + s[j]) * invT;
    {
      float4 a, b;
      a.x = cvn[0]; a.y = cvn[1]; a.z = cvn[2]; a.w = cvn[3];
      b.x = cvn[4]; b.y = cvn[5]; b.z = cvn[6]; b.w = cvn[7];
      *(float4*)(cdf_s + kbase) = a;
      *(float4*)(cdf_s + kbase + 4) = b;
    }
    cend[tid] = cvn[PT - 1];
    if (tid == BLOCK - 1) bcI[0] = (int)(cvn[PT - 1] * NBF);
    {
      int4 z4; z4.x = z4.y = z4.z = z4.w = 0;
      *(int4*)(L_s + kbase) = z4;
      *(int4*)(L_s + kbase + 4) = z4;
    }
    if (tid == 0)
      acc += __logf(total) - 9.0109133472792886f   // log(K)
             - 0.5f * (1.8378770664093453f + xt * xt);
    __syncthreads();  // B2

    // ---- C2a: scatter. Covering particle i writes L[flo+1] = i. Race-free:
    // boundaries telescope on STORED values (cend), clamps only kill top writes.
    {
      const float cprev = tid ? cend[tid - 1] : 0.f;
      int flo = (int)(cprev * NBF);
#pragma unroll
      for (int j = 0; j < PT; ++j) {
        int fhi = (int)(cvn[j] * NBF);
        if (fhi > NBUCK - 1) fhi = NBUCK - 1;
        if (fhi > flo) L_s[flo + 1] = kbase + j;
        flo = fhi;
      }
    }
    __syncthreads();  // B2b

    // ---- C2b: local + wave max-scan over scattered L.
    int4 ra = *(const int4*)(L_s + kbase);
    int4 rb = *(const int4*)(L_s + kbase + 4);
    int c1 = max(ra.x, ra.y);
    int c2 = max(c1, ra.z);
    int c3 = max(c2, ra.w);
    int c4 = max(c3, rb.x);
    int c5 = max(c4, rb.y);
    int c6 = max(c5, rb.z);
    int c7 = max(c6, rb.w);
    const int mincl = wscan64_max(c7);
    int mexcl = __shfl_up(mincl, 1);
    if (lane == 0) mexcl = 0;
    if (lane == 63) redi[wid] = mincl;
    __syncthreads();  // B2c

    // ---- C2c: cross-wave max, finalize L in place + top-fix.
    {
      int mv = rscan16_max(redi[lane & 15]);
      const int crosspre = wid ? __builtin_amdgcn_readlane(mv, wid - 1) : 0;
      const int fhiLast = bcI[0];
      int m = max(crosspre, mexcl);
      int4 oa, ob;
      m = max(m, ra.x); oa.x = (kbase + 0 > fhiLast) ? (KP - 1) : m;
      m = max(m, ra.y); oa.y = (kbase + 1 > fhiLast) ? (KP - 1) : m;
      m = max(m, ra.z); oa.z = (kbase + 2 > fhiLast) ? (KP - 1) : m;
      m = max(m, ra.w); oa.w = (kbase + 3 > fhiLast) ? (KP - 1) : m;
      m = max(m, rb.x); ob.x = (kbase + 4 > fhiLast) ? (KP - 1) : m;
      m = max(m, rb.y); ob.y = (kbase + 5 > fhiLast) ? (KP - 1) : m;
      m = max(m, rb.z); ob.z = (kbase + 6 > fhiLast) ? (KP - 1) : m;
      m = max(m, rb.w); ob.w = (kbase + 7 > fhiLast) ? (KP - 1) : m;
      *(int4*)(L_s + kbase) = oa;
      *(int4*)(L_s + kbase + 4) = ob;
    }
    __syncthreads();  // B3

    // ---- D: window setup from bucket table; target is u directly.
    // Invariant: answer in [lo, lo+len]; any in-window probe preserves it.
    int lo[PT], len[PT];
    float tg[PT], fr0[PT];
#pragma unroll
    for (int j = 0; j < PT; ++j) {
      tg[j] = uv[j];
      const float fb = uv[j] * NBF;
      int b = (int)fb;
      b = min(b, NBUCK - 1);
      fr0[j] = fb - (float)b;  // free interpolation coordinate in bucket
      const int i0 = L_s[b];
      const int i1 = L_s[b + 1];
      lo[j] = i0;
      len[j] = i1 - i0;
    }
    // Round 0: interpolated probe (CLT: cuts dense windows to ~sqrt(len)).
    int anylen = 0;
#pragma unroll
    for (int j = 0; j < PT; ++j) {
      int off = (int)(fr0[j] * (float)len[j]);
      off = min(off, len[j] - 1);
      off = max(off, 0);
      const float c = cdf_s[lo[j] + off];
      const bool adv = (c < tg[j]) & (len[j] > 0);  // freeze len==0 slots
      lo[j] = adv ? lo[j] + off + 1 : lo[j];
      len[j] = adv ? len[j] - off - 1 : (len[j] > 0 ? off : 0);
      anylen |= len[j];
    }
    // Binary rounds; wave cost = max_j ceil(log2(len+1)).
    while (anylen) {
      anylen = 0;
#pragma unroll
      for (int j = 0; j < PT; ++j) {
        const int half = len[j] >> 1;
        const float c = cdf_s[lo[j] + half];
        const bool adv = (c < tg[j]) & (len[j] > 0);
        lo[j] = adv ? lo[j] + half + 1 : lo[j];
        len[j] = adv ? len[j] - half - 1 : half;
        anylen |= len[j];
      }
    }

    // ---- E: gather from wcur, write to wnxt (double buffer: no barrier).
    float nw[PT];
#pragma unroll
    for (int j = 0; j < PT; ++j) nw[j] = wcur[lo[j]];
    {
      float4 a, b;
      a.x = nw[0]; a.y = nw[1]; a.z = nw[2]; a.w = nw[3];
      b.x = nw[4]; b.y = nw[5]; b.z = nw[6]; b.w = nw[7];
      *(float4*)(wnxt + kbase) = a;
      *(float4*)(wnxt + kbase + 4) = b;
    }
#pragma unroll
    for (int j = 0; j < PT; ++j) wv[j] = nw[j];
    float* tmp = wcur; wcur = wnxt; wnxt = tmp;
  }

  if (tid == 0) out[0] = acc;
}

// ---------------------------------------------------------------------------
extern "C" void kernel_launch(void* const* d_in, const int* in_sizes, int n_in,
                              void* d_out, int out_size, void* d_ws, size_t ws_size,
                              hipStream_t stream) {
  const float* x = (const float*)d_in[0];   // [T]
  const float* w0 = (const float*)d_in[1];  // [K]
  const float* z = (const float*)d_in[2];   // [K,T]
  const float* u = (const float*)d_in[3];   // [T,K]
  float* out = (float*)d_out;

  const size_t zbytes = (size_t)KP * TSTEPS * sizeof(float);
  const size_t shmem =
      (size_t)(3 * KP + BLOCK + NWAVES + NWAVES + 4 + NBUCK + 1) * sizeof(float);

  if (ws_size >= zbytes) {
    float* zT = (float*)d_ws;
    transpose_k<<<dim3(TSTEPS / 32, KP / 32), dim3(32, 8), 0, stream>>>(z, zT);
    smc_scan<true><<<1, BLOCK, shmem, stream>>>(x, w0, zT, u, out);
  } else {
    smc_scan<false><<<1, BLOCK, shmem, stream>>>(x, w0, z, u, out);
  }
}